// Round 3
// baseline (1586.120 us; speedup 1.0000x reference)
//
#include <hip/hip_runtime.h>

#define N_USERS 100000
#define N_ITEMS 200000
#define N_TOTAL 300000
#define N_EDGES 6000000
#define D 64

#define PAD 16   // ints per counter: one counter per 64B line (kills line contention)

#define SCAN_THREADS 256
#define SCAN_ITEMS 4
#define SCAN_TILE (SCAN_THREADS * SCAN_ITEMS)             // 1024
#define SCAN_NBLK ((N_TOTAL + SCAN_TILE - 1) / SCAN_TILE) // 293

// ---------------------------------------------------------------------------
// trans = all_feat @ W^T + b  (one wave per row). If `out` non-null, also
// writes identity residual (fallback path only).
// ---------------------------------------------------------------------------
__global__ __launch_bounds__(256) void linear_kernel(
    const float* __restrict__ user_feat,
    const float* __restrict__ item_feat,
    const float* __restrict__ W,
    const float* __restrict__ b,
    float* __restrict__ trans,
    float* __restrict__ out)
{
    __shared__ float Ws[D][D + 1];
    __shared__ float bs[D];
    const int t = threadIdx.x;
    for (int i = t; i < D * D; i += 256) Ws[i >> 6][i & 63] = W[i];
    if (t < D) bs[t] = b[t];
    __syncthreads();

    const int lane = t & 63;
    const int row  = blockIdx.x * 4 + (t >> 6);
    if (row >= N_TOTAL) return;

    const float* feat = (row < N_USERS)
        ? user_feat + (size_t)row * D
        : item_feat + (size_t)(row - N_USERS) * D;

    const float fv = feat[lane];
    float acc = bs[lane];
    #pragma unroll
    for (int k = 0; k < D; ++k)
        acc = fmaf(__shfl(fv, k, 64), Ws[lane][k], acc);

    const size_t off = (size_t)row * D + lane;
    trans[off] = acc;
    if (out) out[off] = fv;
}

// ---------------------------------------------------------------------------
// CSR build with line-padded counters.
// ---------------------------------------------------------------------------
__global__ __launch_bounds__(256) void hist_pad_kernel(
    const int* __restrict__ A_row, int* __restrict__ cnt)
{
    const int e = blockIdx.x * 256 + threadIdx.x;
    if (e < N_EDGES) atomicAdd(&cnt[(size_t)A_row[e] * PAD], 1);
}

// exclusive scan over padded counts -> compact[] (row starts) AND cnt[] (cursors)
__global__ __launch_bounds__(SCAN_THREADS) void scan_block_kernel(
    int* __restrict__ cnt, int* __restrict__ compact, int* __restrict__ bsum)
{
    __shared__ int s[SCAN_THREADS];
    const int t    = threadIdx.x;
    const int base = blockIdx.x * SCAN_TILE + t * SCAN_ITEMS;

    int v[SCAN_ITEMS];
    int sum = 0;
    #pragma unroll
    for (int i = 0; i < SCAN_ITEMS; ++i) {
        const int idx = base + i;
        v[i] = (idx < N_TOTAL) ? cnt[(size_t)idx * PAD] : 0;
        sum += v[i];
    }
    s[t] = sum;
    __syncthreads();
    for (int d = 1; d < SCAN_THREADS; d <<= 1) {
        const int x = (t >= d) ? s[t - d] : 0;
        __syncthreads();
        s[t] += x;
        __syncthreads();
    }
    int run = (t == 0) ? 0 : s[t - 1];
    #pragma unroll
    for (int i = 0; i < SCAN_ITEMS; ++i) {
        const int idx = base + i;
        if (idx < N_TOTAL) {
            compact[idx] = run;
            cnt[(size_t)idx * PAD] = run;
        }
        run += v[i];
    }
    if (t == SCAN_THREADS - 1) bsum[blockIdx.x] = s[t];
}

__global__ __launch_bounds__(512) void scan_sums_kernel(int* __restrict__ bsum)
{
    __shared__ int s[512];
    const int t = threadIdx.x;
    s[t] = (t < SCAN_NBLK) ? bsum[t] : 0;
    __syncthreads();
    for (int d = 1; d < 512; d <<= 1) {
        const int x = (t >= d) ? s[t - d] : 0;
        __syncthreads();
        s[t] += x;
        __syncthreads();
    }
    if (t < SCAN_NBLK) bsum[t] = (t == 0) ? 0 : s[t - 1];
}

__global__ __launch_bounds__(256) void scan_add_kernel(
    int* __restrict__ cnt, int* __restrict__ compact, const int* __restrict__ bsum)
{
    const int i = blockIdx.x * 256 + threadIdx.x;
    if (i < N_TOTAL) {
        const int add = bsum[i / SCAN_TILE];
        compact[i] += add;
        cnt[(size_t)i * PAD] += add;
    }
}

// cursor fetch-inc on padded counters; store 4B edge-id.
// After this kernel cnt[r*PAD] == end of row r's segment.
__global__ __launch_bounds__(256) void scatter_eid_kernel(
    const int* __restrict__ A_row,
    int* __restrict__ cnt,
    int* __restrict__ eids)
{
    const int e = blockIdx.x * 256 + threadIdx.x;
    if (e >= N_EDGES) return;
    const int pos = atomicAdd(&cnt[(size_t)A_row[e] * PAD], 1);
    eids[pos] = e;
}

// ---------------------------------------------------------------------------
// Pull: one wave per row, lane = column. eid -> (col, val) broadcast loads
// (L3-resident), 4-way unrolled for MLP. No fp32 atomics anywhere.
// ---------------------------------------------------------------------------
__global__ __launch_bounds__(256) void pull_kernel(
    const int*   __restrict__ compact,
    const int*   __restrict__ cnt,
    const int*   __restrict__ eids,
    const int*   __restrict__ A_col,
    const float* __restrict__ A_val,
    const float* __restrict__ trans,
    const float* __restrict__ user_feat,
    const float* __restrict__ item_feat,
    float* __restrict__ out)
{
    const int lane = threadIdx.x & 63;
    const int row  = blockIdx.x * 4 + (threadIdx.x >> 6);
    if (row >= N_TOTAL) return;

    const float* feat = (row < N_USERS)
        ? user_feat + (size_t)row * D
        : item_feat + (size_t)(row - N_USERS) * D;

    float acc0 = feat[lane];          // identity residual
    float acc1 = 0.0f, acc2 = 0.0f, acc3 = 0.0f;

    const int s   = compact[row];
    const int end = cnt[(size_t)row * PAD];

    int i = s;
    for (; i + 3 < end; i += 4) {
        const int e0 = eids[i],     e1 = eids[i + 1];
        const int e2 = eids[i + 2], e3 = eids[i + 3];
        const int c0 = A_col[e0], c1 = A_col[e1], c2 = A_col[e2], c3 = A_col[e3];
        const float v0 = A_val[e0], v1 = A_val[e1], v2 = A_val[e2], v3 = A_val[e3];
        acc0 = fmaf(v0, trans[(size_t)c0 * D + lane], acc0);
        acc1 = fmaf(v1, trans[(size_t)c1 * D + lane], acc1);
        acc2 = fmaf(v2, trans[(size_t)c2 * D + lane], acc2);
        acc3 = fmaf(v3, trans[(size_t)c3 * D + lane], acc3);
    }
    for (; i < end; ++i) {
        const int e0 = eids[i];
        acc0 = fmaf(A_val[e0], trans[(size_t)A_col[e0] * D + lane], acc0);
    }
    out[(size_t)row * D + lane] = (acc0 + acc1) + (acc2 + acc3);
}

// ---------------------------------------------------------------------------
// Fallback kernels (small workspace): atomic push path.
// ---------------------------------------------------------------------------
__global__ __launch_bounds__(256) void edge_scatter_kernel(
    const int*   __restrict__ A_row,
    const int*   __restrict__ A_col,
    const float* __restrict__ A_val,
    const float* __restrict__ trans,
    float*       __restrict__ out)
{
    const int lane = threadIdx.x & 63;
    const long long e = ((long long)blockIdx.x * 256 + threadIdx.x) >> 6;
    if (e >= N_EDGES) return;
    atomicAdd(out + (size_t)A_row[e] * D + lane,
              A_val[e] * trans[(size_t)A_col[e] * D + lane]);
}

__global__ __launch_bounds__(256) void init_out_kernel(
    const float* __restrict__ user_feat,
    const float* __restrict__ item_feat,
    float* __restrict__ out)
{
    const size_t i = (size_t)blockIdx.x * 256 + threadIdx.x;
    if (i >= (size_t)N_TOTAL * D) return;
    const size_t urows = (size_t)N_USERS * D;
    out[i] = (i < urows) ? user_feat[i] : item_feat[i - urows];
}

__global__ __launch_bounds__(256) void fused_edge_kernel(
    const int*   __restrict__ A_row,
    const int*   __restrict__ A_col,
    const float* __restrict__ A_val,
    const float* __restrict__ user_feat,
    const float* __restrict__ item_feat,
    const float* __restrict__ W,
    const float* __restrict__ b,
    float*       __restrict__ out)
{
    __shared__ float Ws[D][D + 1];
    __shared__ float bs[D];
    const int t = threadIdx.x;
    for (int i = t; i < D * D; i += 256) Ws[i >> 6][i & 63] = W[i];
    if (t < D) bs[t] = b[t];
    __syncthreads();

    const int lane = t & 63;
    const long long e = ((long long)blockIdx.x * 256 + t) >> 6;
    if (e >= N_EDGES) return;

    const int   r = A_row[e];
    const int   c = A_col[e];
    const float v = A_val[e];

    const float* feat = (c < N_USERS)
        ? user_feat + (size_t)c * D
        : item_feat + (size_t)(c - N_USERS) * D;

    const float fv = feat[lane];
    float acc = bs[lane];
    #pragma unroll
    for (int k = 0; k < D; ++k)
        acc = fmaf(__shfl(fv, k, 64), Ws[lane][k], acc);

    atomicAdd(out + (size_t)r * D + lane, v * acc);
}

// ---------------------------------------------------------------------------
extern "C" void kernel_launch(void* const* d_in, const int* in_sizes, int n_in,
                              void* d_out, int out_size, void* d_ws, size_t ws_size,
                              hipStream_t stream)
{
    const int*   A_row     = (const int*)  d_in[0];
    const int*   A_col     = (const int*)  d_in[1];
    const float* A_val     = (const float*)d_in[2];
    const float* user_feat = (const float*)d_in[3];
    const float* item_feat = (const float*)d_in[4];
    const float* W         = (const float*)d_in[5];
    const float* b         = (const float*)d_in[6];
    float*       out       = (float*)d_out;

    const size_t trans_bytes   = (size_t)N_TOTAL * D * sizeof(float);          // 76.8 MB
    const size_t cnt_bytes     = ((size_t)N_TOTAL * PAD * sizeof(int) + 255) & ~(size_t)255; // 19.2 MB
    const size_t compact_bytes = ((size_t)N_TOTAL * sizeof(int) + 255) & ~(size_t)255;       // 1.2 MB
    const size_t bsum_bytes    = ((size_t)SCAN_NBLK * sizeof(int) + 255) & ~(size_t)255;
    const size_t eids_bytes    = (size_t)N_EDGES * sizeof(int);                // 24 MB
    const size_t csr_total = trans_bytes + cnt_bytes + compact_bytes + bsum_bytes + eids_bytes; // ~121.2 MB

    const int edge_blocks = (N_EDGES + 255) / 256;
    const int row_blocks  = (N_TOTAL + 3) / 4;

    if (ws_size >= csr_total) {
        char* p = (char*)d_ws;
        float* trans   = (float*)p;  p += trans_bytes;
        int*   cnt     = (int*)p;    p += cnt_bytes;
        int*   compact = (int*)p;    p += compact_bytes;
        int*   bsum    = (int*)p;    p += bsum_bytes;
        int*   eids    = (int*)p;

        hipMemsetAsync(cnt, 0, (size_t)N_TOTAL * PAD * sizeof(int), stream);
        linear_kernel<<<row_blocks, 256, 0, stream>>>(
            user_feat, item_feat, W, b, trans, nullptr);
        hist_pad_kernel<<<edge_blocks, 256, 0, stream>>>(A_row, cnt);
        scan_block_kernel<<<SCAN_NBLK, SCAN_THREADS, 0, stream>>>(cnt, compact, bsum);
        scan_sums_kernel<<<1, 512, 0, stream>>>(bsum);
        scan_add_kernel<<<(N_TOTAL + 255) / 256, 256, 0, stream>>>(cnt, compact, bsum);
        scatter_eid_kernel<<<edge_blocks, 256, 0, stream>>>(A_row, cnt, eids);
        pull_kernel<<<row_blocks, 256, 0, stream>>>(
            compact, cnt, eids, A_col, A_val, trans, user_feat, item_feat, out);
    } else if (ws_size >= trans_bytes) {
        float* trans = (float*)d_ws;
        linear_kernel<<<row_blocks, 256, 0, stream>>>(
            user_feat, item_feat, W, b, trans, out);
        edge_scatter_kernel<<<N_EDGES / 4, 256, 0, stream>>>(
            A_row, A_col, A_val, trans, out);
    } else {
        const size_t total = (size_t)N_TOTAL * D;
        init_out_kernel<<<(int)((total + 255) / 256), 256, 0, stream>>>(
            user_feat, item_feat, out);
        fused_edge_kernel<<<N_EDGES / 4, 256, 0, stream>>>(
            A_row, A_col, A_val, user_feat, item_feat, W, b, out);
    }
}

// Round 4
// 1116.055 us; speedup vs baseline: 1.4212x; 1.4212x over previous
//
#include <hip/hip_runtime.h>

#define N_USERS 100000
#define N_ITEMS 200000
#define N_TOTAL 300000
#define N_EDGES 6000000
#define D 64

#define SCAN_THREADS 256
#define SCAN_ITEMS 4
#define SCAN_TILE (SCAN_THREADS * SCAN_ITEMS)             // 1024
#define SCAN_NBLK ((N_TOTAL + SCAN_TILE - 1) / SCAN_TILE) // 293

// ---------------------------------------------------------------------------
// trans = all_feat @ W^T + b  (one wave per row). If `out` non-null, also
// writes identity residual (fallback path only).
// ---------------------------------------------------------------------------
__global__ __launch_bounds__(256) void linear_kernel(
    const float* __restrict__ user_feat,
    const float* __restrict__ item_feat,
    const float* __restrict__ W,
    const float* __restrict__ b,
    float* __restrict__ trans,
    float* __restrict__ out)
{
    __shared__ float Ws[D][D + 1];
    __shared__ float bs[D];
    const int t = threadIdx.x;
    for (int i = t; i < D * D; i += 256) Ws[i >> 6][i & 63] = W[i];
    if (t < D) bs[t] = b[t];
    __syncthreads();

    const int lane = t & 63;
    const int row  = blockIdx.x * 4 + (t >> 6);
    if (row >= N_TOTAL) return;

    const float* feat = (row < N_USERS)
        ? user_feat + (size_t)row * D
        : item_feat + (size_t)(row - N_USERS) * D;

    const float fv = feat[lane];
    float acc = bs[lane];
    #pragma unroll
    for (int k = 0; k < D; ++k)
        acc = fmaf(__shfl(fv, k, 64), Ws[lane][k], acc);

    const size_t off = (size_t)row * D + lane;
    trans[off] = acc;
    if (out) out[off] = fv;
}

// ---------------------------------------------------------------------------
// Histogram: 4 edges per thread (int4 load, 4 independent non-returning
// atomics in flight). Counters compact (1.2 MB, L2-resident).
// ---------------------------------------------------------------------------
__global__ __launch_bounds__(256) void hist_kernel(
    const int* __restrict__ A_row, int* __restrict__ rowoff)
{
    const int e0 = (blockIdx.x * 256 + threadIdx.x) * 4;
    if (e0 >= N_EDGES) return;
    const int4 r = *reinterpret_cast<const int4*>(A_row + e0);
    atomicAdd(&rowoff[r.x], 1);
    atomicAdd(&rowoff[r.y], 1);
    atomicAdd(&rowoff[r.z], 1);
    atomicAdd(&rowoff[r.w], 1);
}

// ---------------------------------------------------------------------------
// Exclusive scan over rowoff (in place): block scan -> block sums -> add.
// ---------------------------------------------------------------------------
__global__ __launch_bounds__(SCAN_THREADS) void scan_block_kernel(
    int* __restrict__ rowoff, int* __restrict__ bsum)
{
    __shared__ int s[SCAN_THREADS];
    const int t    = threadIdx.x;
    const int base = blockIdx.x * SCAN_TILE + t * SCAN_ITEMS;

    int v[SCAN_ITEMS];
    int sum = 0;
    #pragma unroll
    for (int i = 0; i < SCAN_ITEMS; ++i) {
        const int idx = base + i;
        v[i] = (idx < N_TOTAL) ? rowoff[idx] : 0;
        sum += v[i];
    }
    s[t] = sum;
    __syncthreads();
    for (int d = 1; d < SCAN_THREADS; d <<= 1) {
        const int x = (t >= d) ? s[t - d] : 0;
        __syncthreads();
        s[t] += x;
        __syncthreads();
    }
    int run = (t == 0) ? 0 : s[t - 1];
    #pragma unroll
    for (int i = 0; i < SCAN_ITEMS; ++i) {
        const int idx = base + i;
        if (idx < N_TOTAL) rowoff[idx] = run;
        run += v[i];
    }
    if (t == SCAN_THREADS - 1) bsum[blockIdx.x] = s[t];
}

__global__ __launch_bounds__(512) void scan_sums_kernel(int* __restrict__ bsum)
{
    __shared__ int s[512];
    const int t = threadIdx.x;
    s[t] = (t < SCAN_NBLK) ? bsum[t] : 0;
    __syncthreads();
    for (int d = 1; d < 512; d <<= 1) {
        const int x = (t >= d) ? s[t - d] : 0;
        __syncthreads();
        s[t] += x;
        __syncthreads();
    }
    if (t < SCAN_NBLK) bsum[t] = (t == 0) ? 0 : s[t - 1];
}

__global__ __launch_bounds__(256) void scan_add_kernel(
    int* __restrict__ rowoff, const int* __restrict__ bsum)
{
    const int i = blockIdx.x * 256 + threadIdx.x;
    if (i < N_TOTAL) rowoff[i] += bsum[i / SCAN_TILE];
}

// ---------------------------------------------------------------------------
// Scatter: 4 edges per thread. 4 independent {returning atomic -> store}
// chains in flight per thread (4x MLP on the latency chain). Packed (col,val)
// payload so pull has only a 2-level load chain.
// After this kernel rowoff[r] == end of row r's segment.
// ---------------------------------------------------------------------------
__global__ __launch_bounds__(256) void scatter_kernel(
    const int*   __restrict__ A_row,
    const int*   __restrict__ A_col,
    const float* __restrict__ A_val,
    int*  __restrict__ rowoff,
    int2* __restrict__ epack)
{
    const int e0 = (blockIdx.x * 256 + threadIdx.x) * 4;
    if (e0 >= N_EDGES) return;
    const int4   r = *reinterpret_cast<const int4*>(A_row + e0);
    const int4   c = *reinterpret_cast<const int4*>(A_col + e0);
    const float4 v = *reinterpret_cast<const float4*>(A_val + e0);

    const int p0 = atomicAdd(&rowoff[r.x], 1);
    const int p1 = atomicAdd(&rowoff[r.y], 1);
    const int p2 = atomicAdd(&rowoff[r.z], 1);
    const int p3 = atomicAdd(&rowoff[r.w], 1);

    epack[p0] = make_int2(c.x, __float_as_int(v.x));
    epack[p1] = make_int2(c.y, __float_as_int(v.y));
    epack[p2] = make_int2(c.z, __float_as_int(v.z));
    epack[p3] = make_int2(c.w, __float_as_int(v.w));
}

// ---------------------------------------------------------------------------
// Pull: one wave per row, lane = column. 8-wide unroll: 8 uniform epack loads
// (1 cache line) then 8 independent 256B gathers in flight. No fp32 atomics.
// ---------------------------------------------------------------------------
__global__ __launch_bounds__(256) void pull_kernel(
    const int*   __restrict__ rowoff,
    const int2*  __restrict__ epack,
    const float* __restrict__ trans,
    const float* __restrict__ user_feat,
    const float* __restrict__ item_feat,
    float* __restrict__ out)
{
    const int lane = threadIdx.x & 63;
    const int row  = blockIdx.x * 4 + (threadIdx.x >> 6);
    if (row >= N_TOTAL) return;

    const float* feat = (row < N_USERS)
        ? user_feat + (size_t)row * D
        : item_feat + (size_t)(row - N_USERS) * D;

    float a0 = feat[lane];            // identity residual
    float a1 = 0.f, a2 = 0.f, a3 = 0.f, a4 = 0.f, a5 = 0.f, a6 = 0.f, a7 = 0.f;

    const int s   = (row == 0) ? 0 : rowoff[row - 1];
    const int end = rowoff[row];

    int i = s;
    for (; i + 7 < end; i += 8) {
        const int2 p0 = epack[i    ], p1 = epack[i + 1];
        const int2 p2 = epack[i + 2], p3 = epack[i + 3];
        const int2 p4 = epack[i + 4], p5 = epack[i + 5];
        const int2 p6 = epack[i + 6], p7 = epack[i + 7];
        const float t0 = trans[(size_t)p0.x * D + lane];
        const float t1 = trans[(size_t)p1.x * D + lane];
        const float t2 = trans[(size_t)p2.x * D + lane];
        const float t3 = trans[(size_t)p3.x * D + lane];
        const float t4 = trans[(size_t)p4.x * D + lane];
        const float t5 = trans[(size_t)p5.x * D + lane];
        const float t6 = trans[(size_t)p6.x * D + lane];
        const float t7 = trans[(size_t)p7.x * D + lane];
        a0 = fmaf(__int_as_float(p0.y), t0, a0);
        a1 = fmaf(__int_as_float(p1.y), t1, a1);
        a2 = fmaf(__int_as_float(p2.y), t2, a2);
        a3 = fmaf(__int_as_float(p3.y), t3, a3);
        a4 = fmaf(__int_as_float(p4.y), t4, a4);
        a5 = fmaf(__int_as_float(p5.y), t5, a5);
        a6 = fmaf(__int_as_float(p6.y), t6, a6);
        a7 = fmaf(__int_as_float(p7.y), t7, a7);
    }
    for (; i < end; ++i) {
        const int2 p = epack[i];
        a0 = fmaf(__int_as_float(p.y), trans[(size_t)p.x * D + lane], a0);
    }
    out[(size_t)row * D + lane] = ((a0 + a1) + (a2 + a3)) + ((a4 + a5) + (a6 + a7));
}

// ---------------------------------------------------------------------------
// Fallback kernels (small workspace): atomic push path.
// ---------------------------------------------------------------------------
__global__ __launch_bounds__(256) void edge_scatter_kernel(
    const int*   __restrict__ A_row,
    const int*   __restrict__ A_col,
    const float* __restrict__ A_val,
    const float* __restrict__ trans,
    float*       __restrict__ out)
{
    const int lane = threadIdx.x & 63;
    const long long e = ((long long)blockIdx.x * 256 + threadIdx.x) >> 6;
    if (e >= N_EDGES) return;
    atomicAdd(out + (size_t)A_row[e] * D + lane,
              A_val[e] * trans[(size_t)A_col[e] * D + lane]);
}

__global__ __launch_bounds__(256) void init_out_kernel(
    const float* __restrict__ user_feat,
    const float* __restrict__ item_feat,
    float* __restrict__ out)
{
    const size_t i = (size_t)blockIdx.x * 256 + threadIdx.x;
    if (i >= (size_t)N_TOTAL * D) return;
    const size_t urows = (size_t)N_USERS * D;
    out[i] = (i < urows) ? user_feat[i] : item_feat[i - urows];
}

__global__ __launch_bounds__(256) void fused_edge_kernel(
    const int*   __restrict__ A_row,
    const int*   __restrict__ A_col,
    const float* __restrict__ A_val,
    const float* __restrict__ user_feat,
    const float* __restrict__ item_feat,
    const float* __restrict__ W,
    const float* __restrict__ b,
    float*       __restrict__ out)
{
    __shared__ float Ws[D][D + 1];
    __shared__ float bs[D];
    const int t = threadIdx.x;
    for (int i = t; i < D * D; i += 256) Ws[i >> 6][i & 63] = W[i];
    if (t < D) bs[t] = b[t];
    __syncthreads();

    const int lane = t & 63;
    const long long e = ((long long)blockIdx.x * 256 + t) >> 6;
    if (e >= N_EDGES) return;

    const int   r = A_row[e];
    const int   c = A_col[e];
    const float v = A_val[e];

    const float* feat = (c < N_USERS)
        ? user_feat + (size_t)c * D
        : item_feat + (size_t)(c - N_USERS) * D;

    const float fv = feat[lane];
    float acc = bs[lane];
    #pragma unroll
    for (int k = 0; k < D; ++k)
        acc = fmaf(__shfl(fv, k, 64), Ws[lane][k], acc);

    atomicAdd(out + (size_t)r * D + lane, v * acc);
}

// ---------------------------------------------------------------------------
extern "C" void kernel_launch(void* const* d_in, const int* in_sizes, int n_in,
                              void* d_out, int out_size, void* d_ws, size_t ws_size,
                              hipStream_t stream)
{
    const int*   A_row     = (const int*)  d_in[0];
    const int*   A_col     = (const int*)  d_in[1];
    const float* A_val     = (const float*)d_in[2];
    const float* user_feat = (const float*)d_in[3];
    const float* item_feat = (const float*)d_in[4];
    const float* W         = (const float*)d_in[5];
    const float* b         = (const float*)d_in[6];
    float*       out       = (float*)d_out;

    const size_t trans_bytes  = (size_t)N_TOTAL * D * sizeof(float);        // 76.8 MB
    const size_t rowoff_bytes = ((size_t)N_TOTAL * sizeof(int) + 255) & ~(size_t)255;
    const size_t bsum_bytes   = ((size_t)SCAN_NBLK * sizeof(int) + 255) & ~(size_t)255;
    const size_t epack_bytes  = (size_t)N_EDGES * sizeof(int2);             // 48 MB
    const size_t csr_total    = trans_bytes + rowoff_bytes + bsum_bytes + epack_bytes; // ~126.1 MB (same as passing R2)

    const int row_blocks   = (N_TOTAL + 3) / 4;
    const int quad_blocks  = (N_EDGES / 4 + 255) / 256;   // 4 edges per thread

    if (ws_size >= csr_total) {
        char* p = (char*)d_ws;
        float* trans  = (float*)p;  p += trans_bytes;
        int*   rowoff = (int*)p;    p += rowoff_bytes;
        int*   bsum   = (int*)p;    p += bsum_bytes;
        int2*  epack  = (int2*)p;

        hipMemsetAsync(rowoff, 0, (size_t)N_TOTAL * sizeof(int), stream);
        linear_kernel<<<row_blocks, 256, 0, stream>>>(
            user_feat, item_feat, W, b, trans, nullptr);
        hist_kernel<<<quad_blocks, 256, 0, stream>>>(A_row, rowoff);
        scan_block_kernel<<<SCAN_NBLK, SCAN_THREADS, 0, stream>>>(rowoff, bsum);
        scan_sums_kernel<<<1, 512, 0, stream>>>(bsum);
        scan_add_kernel<<<(N_TOTAL + 255) / 256, 256, 0, stream>>>(rowoff, bsum);
        scatter_kernel<<<quad_blocks, 256, 0, stream>>>(
            A_row, A_col, A_val, rowoff, epack);
        pull_kernel<<<row_blocks, 256, 0, stream>>>(
            rowoff, epack, trans, user_feat, item_feat, out);
    } else if (ws_size >= trans_bytes) {
        float* trans = (float*)d_ws;
        linear_kernel<<<row_blocks, 256, 0, stream>>>(
            user_feat, item_feat, W, b, trans, out);
        edge_scatter_kernel<<<N_EDGES / 4, 256, 0, stream>>>(
            A_row, A_col, A_val, trans, out);
    } else {
        const size_t total = (size_t)N_TOTAL * D;
        init_out_kernel<<<(int)((total + 255) / 256), 256, 0, stream>>>(
            user_feat, item_feat, out);
        fused_edge_kernel<<<N_EDGES / 4, 256, 0, stream>>>(
            A_row, A_col, A_val, user_feat, item_feat, W, b, out);
    }
}